// Round 8
// baseline (881.588 us; speedup 1.0000x reference)
//
#include <hip/hip_runtime.h>
#include <hip/hip_bf16.h>
#include <stdint.h>

// ============================================================================
// MultiHeadAttention, B=2 S=2048 D_MODEL=1024 NHEAD=16 D_HEAD=64.
// Inputs fp32 (runtime-sniffed, bf16 fallback); mask encoding classified;
// OUTPUT IS FP32 (rounds 0-7 wrote bf16 into the fp32 d_out buffer — that
// was the sole decorrelator; harness contract: output dtype = reference
// output dtype = float32). Internal compute: bf16 MFMA, fp32 accumulate.
//
// SEMANTICS: faithful to the visible reference. (x @ W.T).reshape(B,16,-1,64)
// on (B,2048,1024) row-major MIXES seq and feature dims:
//   head h   = s >> 7
//   t (2048) = (s & 127)*16 + (o >> 6)
//   d (64)   = o & 63
// Attention runs over t; mask[b, t_q, t_k] aligns with t; True = EXCLUDE.
//
// Pipeline:
//   k_detect : flags[0]=inputs-fp32, flags[1]=mask mode 0:u8 1:i32 2:u16 3:u32
//   k_proj   : z=0,1,2 -> QH/KH [b,h,t,d] and VT [b,h,d,t]  (128x128 GEMM)
//   k_attn   : flash attention per (b,h), 128x128 tiles, online softmax
//   k_outp   : OB @ w_o.T -> d_out (FP32)
// Workspace: flags at 0; QH/KH/VT/OB bf16 8MB each at ws+256.
// ============================================================================

typedef __attribute__((ext_vector_type(8))) short short8;
typedef __attribute__((ext_vector_type(4))) float floatx4;
using bf16 = __hip_bfloat16;

#define MFMA16(a, b, c) __builtin_amdgcn_mfma_f32_16x16x32_bf16(a, b, c, 0, 0, 0)

__device__ __forceinline__ void load_lds16(const bf16* g, bf16* l) {
  __builtin_amdgcn_global_load_lds(
      (const __attribute__((address_space(1))) void*)g,
      (__attribute__((address_space(3))) void*)l, 16, 0, 0);
}

__device__ __forceinline__ float scrub(float x) {
  return (x == x && fabsf(x) < 1e30f) ? x : 0.0f;
}

// ---------------------------------------------------------------------------
__global__ void k_detect(const uint16_t* __restrict__ q,
                         const uint16_t* __restrict__ mask,
                         int* __restrict__ flags) {
  __shared__ int f32, cat;
  const int tid = threadIdx.x;
  if (tid == 0) { f32 = 0; cat = 0; }
  __syncthreads();
  int hit = 0;
  for (int i = tid; i < 16384; i += 256) {
    const int e = (q[i] >> 7) & 0xFF;
    if (e == 0 || e == 0xFF) hit = 1;   // impossible for bf16 N(0,1)
  }
  if (hit) atomicOr(&f32, 1);
  int c = 0;
  for (int i = tid; i < 2048; i += 256) {
    const uint32_t hw = mask[i];
    if (hw == 0x3C00u) c |= 4;                     // f16 1.0
    else if (hw == 0x3F80u) c |= (i & 1) ? 2 : 1;  // bf16(even)/fp32(odd half)
    else if (hw > 1u) c |= 8;                      // packed-byte pattern
  }
  if (c) atomicOr(&cat, c);
  __syncthreads();
  if (tid == 0) {
    flags[0] = f32;
    const int cc = cat;
    int mode;
    if (cc & 4)      mode = 2;
    else if (cc & 1) mode = 2;
    else if (cc & 2) mode = 3;
    else if (cc & 8) mode = 0;
    else             mode = 1;
    flags[1] = mode;
  }
}

// ---------------------------------------------------------------------------
// Tile staging: fill a 128x32 bf16 tile (8KB, row stride 32) from a source
// with row stride 1024 elements.
__device__ __forceinline__ void stage_b16(const bf16* __restrict__ src,
                                          bf16* __restrict__ dst,
                                          int wv, int ln) {
#pragma unroll
  for (int i = 0; i < 2; i++) {
    const int seg = i * 4 + wv;
    const int fb = seg * 1024 + ln * 16;
    const int row = fb >> 6, col = (fb & 63) >> 1;
    load_lds16(src + (size_t)row * 1024 + col, dst + seg * 512);
  }
}

__device__ __forceinline__ void stage_f32(const float* __restrict__ src,
                                          bf16* __restrict__ dst, int tid) {
#pragma unroll
  for (int it = 0; it < 2; ++it) {
    const int e0 = (it * 256 + tid) * 8;
    const int row = e0 >> 5, col = e0 & 31;
    const float* s = src + (size_t)row * 1024 + col;
    const float4 f0 = *(const float4*)s;
    const float4 f1 = *(const float4*)(s + 4);
    union { short8 v; bf16 b[8]; } u;
    u.b[0] = __float2bfloat16(f0.x); u.b[1] = __float2bfloat16(f0.y);
    u.b[2] = __float2bfloat16(f0.z); u.b[3] = __float2bfloat16(f0.w);
    u.b[4] = __float2bfloat16(f1.x); u.b[5] = __float2bfloat16(f1.y);
    u.b[6] = __float2bfloat16(f1.z); u.b[7] = __float2bfloat16(f1.w);
    *(short8*)(dst + e0) = u.v;
  }
}

// ---------------------------------------------------------------------------
// NT GEMM: A[M][1024], W[1024][1024] row-major, C[m][n]=sum_k A[m,k]W[n,k].
// 128x128 tile, BK=32, 4 waves (2x2 of 64x64).
// mode 0: C -> QH/KH [b,h,t,d] reshape-mixed;  mode 1: C -> VT [b,h,d,t];
// mode 2: C -> OutF (FP32, plain row-major).
__device__ __forceinline__ void gemm128(const void* __restrict__ A, int a_f32,
                                        const void* __restrict__ W, int w_f32,
                                        bf16* __restrict__ Out,
                                        float* __restrict__ OutF, int mode) {
  __shared__ bf16 As[128 * 32];
  __shared__ bf16 Bs[128 * 32];
  const int tid = threadIdx.x;
  const int wv = tid >> 6, ln = tid & 63;
  const int m0 = blockIdx.x * 128, n0 = blockIdx.y * 128;
  const int wm = (wv >> 1) * 64, wn = (wv & 1) * 64;
  floatx4 acc[4][4] = {};
  for (int k0 = 0; k0 < 1024; k0 += 32) {
    __syncthreads();
    if (a_f32) stage_f32((const float*)A + (size_t)m0 * 1024 + k0, As, tid);
    else       stage_b16((const bf16*)A + (size_t)m0 * 1024 + k0, As, wv, ln);
    if (w_f32) stage_f32((const float*)W + (size_t)n0 * 1024 + k0, Bs, tid);
    else       stage_b16((const bf16*)W + (size_t)n0 * 1024 + k0, Bs, wv, ln);
    __syncthreads();
    const short* Ap = (const short*)As;
    const short* Bp = (const short*)Bs;
    short8 af[4], bfr[4];
#pragma unroll
    for (int t = 0; t < 4; t++) {
      af[t]  = *(const short8*)(Ap + (wm + t * 16 + (ln & 15)) * 32 + (ln >> 4) * 8);
      bfr[t] = *(const short8*)(Bp + (wn + t * 16 + (ln & 15)) * 32 + (ln >> 4) * 8);
    }
#pragma unroll
    for (int ti = 0; ti < 4; ti++)
#pragma unroll
      for (int tj = 0; tj < 4; tj++)
        acc[ti][tj] = MFMA16(af[ti], bfr[tj], acc[ti][tj]);
  }
  // epilogue: C/D layout col=lane&15, row=(lane>>4)*4+r  [m89-verified]
#pragma unroll
  for (int ti = 0; ti < 4; ti++)
#pragma unroll
    for (int tj = 0; tj < 4; tj++)
#pragma unroll
      for (int r = 0; r < 4; r++) {
        const int m = m0 + wm + ti * 16 + (ln >> 4) * 4 + r;
        const int n = n0 + wn + tj * 16 + (ln & 15);
        if (mode == 2) {
          OutF[(size_t)m * 1024 + n] = scrub(acc[ti][tj][r]);  // FP32 OUT
        } else {
          const int b = m >> 11, s = m & 2047;
          const int h = s >> 7, sl = s & 127;
          const int oc = n >> 6, d = n & 63;
          const int t = sl * 16 + oc;     // reshape-mixed "sequence" index
          size_t idx;
          if (mode == 0) idx = ((size_t)(b * 16 + h) * 2048 + t) * 64 + d;
          else           idx = ((size_t)(b * 16 + h) * 64 + d) * 2048 + t;
          Out[idx] = __float2bfloat16(scrub(acc[ti][tj][r]));
        }
      }
}

__global__ __launch_bounds__(256, 2) void k_proj(
    const void* __restrict__ q, const void* __restrict__ k, const void* __restrict__ v,
    const void* __restrict__ wq, const void* __restrict__ wk, const void* __restrict__ wvv,
    bf16* __restrict__ QH, bf16* __restrict__ KH, bf16* __restrict__ VT,
    const int* __restrict__ flags) {
  const int z = blockIdx.z;
  const int fl = flags[0];
  const void* A = (z == 0) ? q : (z == 1) ? k : v;
  const void* W = (z == 0) ? wq : (z == 1) ? wk : wvv;
  bf16* O = (z == 0) ? QH : (z == 1) ? KH : VT;
  gemm128(A, fl, W, fl, O, nullptr, (z == 2) ? 1 : 0);
}

__global__ __launch_bounds__(256, 2) void k_outp(
    const bf16* __restrict__ A, const void* __restrict__ W,
    float* __restrict__ Out, const int* __restrict__ flags) {
  gemm128(A, 0, W, flags[0], nullptr, Out, 2);
}

// ---------------------------------------------------------------------------
// Flash attention per (b,h). Wave w owns q-rows [32w,32w+32); row stats via
// shfl over 16-lane quads; P round-trips through LDS (C->A layout, m120).
// Mask: nonzero = EXCLUDE (faithful to reference where(mask, -inf, u)).
__global__ void k_attn(const bf16* __restrict__ QH, const bf16* __restrict__ KH,
                       const bf16* __restrict__ VT, const void* __restrict__ maskp,
                       const int* __restrict__ flags, bf16* __restrict__ OB) {
  constexpr int S = 2048, D = 64;
  constexpr float NEG = -30000.0f;
  __shared__ bf16 Qs[128 * 64];  // [t][d]
  __shared__ bf16 Ks[128 * 64];  // [t][d]
  __shared__ bf16 Vs[64 * 128];  // [d][t]
  __shared__ bf16 Ps[128 * 128]; // [q][k]
  const int tid = threadIdx.x, wv = tid >> 6, ln = tid & 63;
  const int q0 = blockIdx.x * 128;
  const int bh = blockIdx.y, b = bh >> 4, h = bh & 15;
  const int mmode = flags[1];
  const uint8_t*  mb = (const uint8_t*)maskp;
  const int*      mi = (const int*)maskp;
  const uint16_t* mh = (const uint16_t*)maskp;
  const uint32_t* mw = (const uint32_t*)maskp;
  const size_t mbase = (size_t)b * S * S;

  const bf16* Qg = QH + ((size_t)bh * S + q0) * D;
#pragma unroll
  for (int i = 0; i < 4; i++) {
    const int e = (i * 4 + wv) * 512 + ln * 8;
    *(short8*)(Qs + e) = *(const short8*)(Qg + e);
  }
  __syncthreads();
  short8 qf[2][2];
  {
    const short* Qp = (const short*)Qs;
#pragma unroll
    for (int ti = 0; ti < 2; ti++)
#pragma unroll
      for (int kc = 0; kc < 2; kc++)
        qf[ti][kc] = *(const short8*)(Qp + (wv * 32 + ti * 16 + (ln & 15)) * 64 + kc * 32 + (ln >> 4) * 8);
  }
  float mst[2][4], lst[2][4];
  floatx4 oacc[2][4] = {};
#pragma unroll
  for (int ti = 0; ti < 2; ti++)
#pragma unroll
    for (int r = 0; r < 4; r++) { mst[ti][r] = NEG; lst[ti][r] = 0.f; }

  for (int kt = 0; kt < 16; kt++) {
    __syncthreads();
    const bf16* Kg = KH + ((size_t)bh * S + kt * 128) * D;
#pragma unroll
    for (int i = 0; i < 4; i++) {
      const int e = (i * 4 + wv) * 512 + ln * 8;
      *(short8*)(Ks + e) = *(const short8*)(Kg + e);
    }
    const bf16* Vg = VT + (size_t)bh * D * S + kt * 128;
#pragma unroll
    for (int i = 0; i < 4; i++) {
      const int fb = ((i * 4 + wv) * 64 + ln) * 16;
      const int dd = fb >> 8, cb = (fb & 255) >> 1;
      *(short8*)(Vs + dd * 128 + cb) = *(const short8*)(Vg + (size_t)dd * S + cb);
    }
    __syncthreads();

    floatx4 sc[2][8];
    {
      const short* Kp = (const short*)Ks;
#pragma unroll
      for (int tj = 0; tj < 8; tj++) {
        const short8 k0f = *(const short8*)(Kp + (tj * 16 + (ln & 15)) * 64 + (ln >> 4) * 8);
        const short8 k1f = *(const short8*)(Kp + (tj * 16 + (ln & 15)) * 64 + 32 + (ln >> 4) * 8);
#pragma unroll
        for (int ti = 0; ti < 2; ti++) {
          floatx4 z = {0.f, 0.f, 0.f, 0.f};
          z = MFMA16(qf[ti][0], k0f, z);
          z = MFMA16(qf[ti][1], k1f, z);
          sc[ti][tj] = z;
        }
      }
    }
    float rmax[2][4];
#pragma unroll
    for (int ti = 0; ti < 2; ti++)
#pragma unroll
      for (int r = 0; r < 4; r++) rmax[ti][r] = NEG;
    const int kb = kt * 128;
#pragma unroll
    for (int ti = 0; ti < 2; ti++) {
      const int qr = q0 + wv * 32 + ti * 16 + (ln >> 4) * 4;
#pragma unroll
      for (int tj = 0; tj < 8; tj++) {
        const int kc = kb + tj * 16 + (ln & 15);
#pragma unroll
        for (int r = 0; r < 4; r++) {
          const size_t midx = mbase + (size_t)(qr + r) * S + kc;
          bool msk;  // nonzero = EXCLUDE (reference polarity)
          if (mmode == 1)      msk = (mi[midx] != 0);
          else if (mmode == 0) msk = (mb[midx] != 0);
          else if (mmode == 2) msk = (mh[midx] != 0);
          else                 msk = (mw[midx] != 0);
          float u = sc[ti][tj][r] * 0.125f;
          u = msk ? NEG : u;
          sc[ti][tj][r] = u;
          rmax[ti][r] = fmaxf(rmax[ti][r], u);
        }
      }
    }
    float alpha[2][4], mnew[2][4];
#pragma unroll
    for (int ti = 0; ti < 2; ti++)
#pragma unroll
      for (int r = 0; r < 4; r++) {
        float v = rmax[ti][r];
        v = fmaxf(v, __shfl_xor(v, 1));
        v = fmaxf(v, __shfl_xor(v, 2));
        v = fmaxf(v, __shfl_xor(v, 4));
        v = fmaxf(v, __shfl_xor(v, 8));
        const float mn = fmaxf(mst[ti][r], v);
        mnew[ti][r] = mn;
        alpha[ti][r] = __expf(fminf(mst[ti][r] - mn, 0.f));
        mst[ti][r] = mn;
      }
    float rsum[2][4] = {};
#pragma unroll
    for (int ti = 0; ti < 2; ti++) {
#pragma unroll
      for (int tj = 0; tj < 8; tj++) {
#pragma unroll
        for (int r = 0; r < 4; r++) {
          const float u = sc[ti][tj][r];
          const float p = (u <= NEG * 0.5f) ? 0.f : __expf(fminf(u - mnew[ti][r], 0.f));
          rsum[ti][r] += p;
          Ps[(wv * 32 + ti * 16 + (ln >> 4) * 4 + r) * 128 + tj * 16 + (ln & 15)] =
              __float2bfloat16(p);
        }
      }
    }
#pragma unroll
    for (int ti = 0; ti < 2; ti++)
#pragma unroll
      for (int r = 0; r < 4; r++) {
        float s = rsum[ti][r];
        s += __shfl_xor(s, 1);
        s += __shfl_xor(s, 2);
        s += __shfl_xor(s, 4);
        s += __shfl_xor(s, 8);
        lst[ti][r] = lst[ti][r] * alpha[ti][r] + s;
#pragma unroll
        for (int tj = 0; tj < 4; tj++) oacc[ti][tj][r] *= alpha[ti][r];
      }
    {
      const short* Pp = (const short*)Ps;
      const short* Vp = (const short*)Vs;
#pragma unroll
      for (int kc = 0; kc < 4; kc++) {
        short8 ap[2];
#pragma unroll
        for (int ti = 0; ti < 2; ti++)
          ap[ti] = *(const short8*)(Pp + (wv * 32 + ti * 16 + (ln & 15)) * 128 + kc * 32 + (ln >> 4) * 8);
#pragma unroll
        for (int tj = 0; tj < 4; tj++) {
          const short8 bv = *(const short8*)(Vp + (tj * 16 + (ln & 15)) * 128 + kc * 32 + (ln >> 4) * 8);
#pragma unroll
          for (int ti = 0; ti < 2; ti++) oacc[ti][tj] = MFMA16(ap[ti], bv, oacc[ti][tj]);
        }
      }
    }
  }
  // ---- epilogue: un-mix (h,t,d) -> (s,o), normalize ----
#pragma unroll
  for (int ti = 0; ti < 2; ti++)
#pragma unroll
    for (int r = 0; r < 4; r++) {
      const float li = lst[ti][r];
      const float rl = (li > 1e-30f) ? 1.f / li : 0.f;
      const int t = q0 + wv * 32 + ti * 16 + (ln >> 4) * 4 + r;
      const int s = h * 128 + (t >> 4);
#pragma unroll
      for (int tj = 0; tj < 4; tj++) {
        const int dcol = tj * 16 + (ln & 15);
        const int o = (t & 15) * 64 + dcol;
        OB[((size_t)b * S + s) * 1024 + o] = __float2bfloat16(scrub(oacc[ti][tj][r] * rl));
      }
    }
}

// ---------------------------------------------------------------------------
extern "C" void kernel_launch(void* const* d_in, const int* in_sizes, int n_in,
                              void* d_out, int out_size, void* d_ws, size_t ws_size,
                              hipStream_t stream) {
  const void* q  = d_in[0];
  const void* k  = d_in[1];
  const void* v  = d_in[2];
  const void* mask = d_in[3];
  const void* wq = d_in[4];
  const void* wk = d_in[5];
  const void* wv = d_in[6];
  const void* wo = d_in[7];
  float* out = (float*)d_out;   // FP32 output (reference output dtype)

  char* ws = (char*)d_ws;
  int* flags = (int*)ws;
  bf16* QH = (bf16*)(ws + 256);
  bf16* KH = QH + 4194304; // 2*16*2048*64
  bf16* VT = KH + 4194304;
  bf16* OB = VT + 4194304; // 32 MB + 256 B total

  k_detect<<<1, 256, 0, stream>>>((const uint16_t*)q, (const uint16_t*)mask, flags);
  k_proj<<<dim3(32, 8, 3), 256, 0, stream>>>(q, k, v, wq, wk, wv, QH, KH, VT, flags);
  k_attn<<<dim3(16, 32), 256, 0, stream>>>(QH, KH, VT, mask, flags, OB);
  k_outp<<<dim3(32, 8), 256, 0, stream>>>(OB, wo, out, flags);
}

// Round 9
// 703.362 us; speedup vs baseline: 1.2534x; 1.2534x over previous
//
#include <hip/hip_runtime.h>
#include <hip/hip_bf16.h>
#include <stdint.h>

// ============================================================================
// MultiHeadAttention, B=2 S=2048 D_MODEL=1024 NHEAD=16 D_HEAD=64.
// Inputs fp32 (runtime-sniffed, bf16 fallback); mask encoding classified;
// output fp32. Internal compute: bf16 MFMA, fp32 accumulate.
//
// SEMANTICS: faithful to the visible reference. (x @ W.T).reshape(B,16,-1,64)
// on (B,2048,1024) row-major MIXES seq and feature dims:
//   head h   = s >> 7
//   t (2048) = (s & 127)*16 + (o >> 6)
//   d (64)   = o & 63
// Attention runs over t; mask[b, t_q, t_k] aligns with t; True = EXCLUDE.
//
// R9: k_attn was spill-bound (VGPR_Count=64 w/o launch_bounds -> 730 MB
// scratch traffic/dispatch, 619 us). Added __launch_bounds__(256,2).
//
// Pipeline:
//   k_detect : flags[0]=inputs-fp32, flags[1]=mask mode 0:u8 1:i32 2:u16 3:u32
//   k_proj   : z=0,1,2 -> QH/KH [b,h,t,d] and VT [b,h,d,t]  (128x128 GEMM)
//   k_attn   : flash attention per (b,h), 128x128 tiles, online softmax
//   k_outp   : OB @ w_o.T -> d_out (FP32)
// Workspace: flags at 0; QH/KH/VT/OB bf16 8MB each at ws+256.
// ============================================================================

typedef __attribute__((ext_vector_type(8))) short short8;
typedef __attribute__((ext_vector_type(4))) float floatx4;
using bf16 = __hip_bfloat16;

#define MFMA16(a, b, c) __builtin_amdgcn_mfma_f32_16x16x32_bf16(a, b, c, 0, 0, 0)

__device__ __forceinline__ void load_lds16(const bf16* g, bf16* l) {
  __builtin_amdgcn_global_load_lds(
      (const __attribute__((address_space(1))) void*)g,
      (__attribute__((address_space(3))) void*)l, 16, 0, 0);
}

__device__ __forceinline__ float scrub(float x) {
  return (x == x && fabsf(x) < 1e30f) ? x : 0.0f;
}

// ---------------------------------------------------------------------------
__global__ void k_detect(const uint16_t* __restrict__ q,
                         const uint16_t* __restrict__ mask,
                         int* __restrict__ flags) {
  __shared__ int f32, cat;
  const int tid = threadIdx.x;
  if (tid == 0) { f32 = 0; cat = 0; }
  __syncthreads();
  int hit = 0;
  for (int i = tid; i < 16384; i += 256) {
    const int e = (q[i] >> 7) & 0xFF;
    if (e == 0 || e == 0xFF) hit = 1;   // impossible for bf16 N(0,1)
  }
  if (hit) atomicOr(&f32, 1);
  int c = 0;
  for (int i = tid; i < 2048; i += 256) {
    const uint32_t hw = mask[i];
    if (hw == 0x3C00u) c |= 4;                     // f16 1.0
    else if (hw == 0x3F80u) c |= (i & 1) ? 2 : 1;  // bf16(even)/fp32(odd half)
    else if (hw > 1u) c |= 8;                      // packed-byte pattern
  }
  if (c) atomicOr(&cat, c);
  __syncthreads();
  if (tid == 0) {
    flags[0] = f32;
    const int cc = cat;
    int mode;
    if (cc & 4)      mode = 2;
    else if (cc & 1) mode = 2;
    else if (cc & 2) mode = 3;
    else if (cc & 8) mode = 0;
    else             mode = 1;
    flags[1] = mode;
  }
}

// ---------------------------------------------------------------------------
// Tile staging: fill a 128x32 bf16 tile (8KB, row stride 32) from a source
// with row stride 1024 elements.
__device__ __forceinline__ void stage_b16(const bf16* __restrict__ src,
                                          bf16* __restrict__ dst,
                                          int wv, int ln) {
#pragma unroll
  for (int i = 0; i < 2; i++) {
    const int seg = i * 4 + wv;
    const int fb = seg * 1024 + ln * 16;
    const int row = fb >> 6, col = (fb & 63) >> 1;
    load_lds16(src + (size_t)row * 1024 + col, dst + seg * 512);
  }
}

__device__ __forceinline__ void stage_f32(const float* __restrict__ src,
                                          bf16* __restrict__ dst, int tid) {
#pragma unroll
  for (int it = 0; it < 2; ++it) {
    const int e0 = (it * 256 + tid) * 8;
    const int row = e0 >> 5, col = e0 & 31;
    const float* s = src + (size_t)row * 1024 + col;
    const float4 f0 = *(const float4*)s;
    const float4 f1 = *(const float4*)(s + 4);
    union { short8 v; bf16 b[8]; } u;
    u.b[0] = __float2bfloat16(f0.x); u.b[1] = __float2bfloat16(f0.y);
    u.b[2] = __float2bfloat16(f0.z); u.b[3] = __float2bfloat16(f0.w);
    u.b[4] = __float2bfloat16(f1.x); u.b[5] = __float2bfloat16(f1.y);
    u.b[6] = __float2bfloat16(f1.z); u.b[7] = __float2bfloat16(f1.w);
    *(short8*)(dst + e0) = u.v;
  }
}

// ---------------------------------------------------------------------------
// NT GEMM: A[M][1024], W[1024][1024] row-major, C[m][n]=sum_k A[m,k]W[n,k].
// 128x128 tile, BK=32, 4 waves (2x2 of 64x64).
// mode 0: C -> QH/KH [b,h,t,d] reshape-mixed;  mode 1: C -> VT [b,h,d,t];
// mode 2: C -> OutF (FP32, plain row-major).
__device__ __forceinline__ void gemm128(const void* __restrict__ A, int a_f32,
                                        const void* __restrict__ W, int w_f32,
                                        bf16* __restrict__ Out,
                                        float* __restrict__ OutF, int mode) {
  __shared__ bf16 As[128 * 32];
  __shared__ bf16 Bs[128 * 32];
  const int tid = threadIdx.x;
  const int wv = tid >> 6, ln = tid & 63;
  const int m0 = blockIdx.x * 128, n0 = blockIdx.y * 128;
  const int wm = (wv >> 1) * 64, wn = (wv & 1) * 64;
  floatx4 acc[4][4] = {};
  for (int k0 = 0; k0 < 1024; k0 += 32) {
    __syncthreads();
    if (a_f32) stage_f32((const float*)A + (size_t)m0 * 1024 + k0, As, tid);
    else       stage_b16((const bf16*)A + (size_t)m0 * 1024 + k0, As, wv, ln);
    if (w_f32) stage_f32((const float*)W + (size_t)n0 * 1024 + k0, Bs, tid);
    else       stage_b16((const bf16*)W + (size_t)n0 * 1024 + k0, Bs, wv, ln);
    __syncthreads();
    const short* Ap = (const short*)As;
    const short* Bp = (const short*)Bs;
    short8 af[4], bfr[4];
#pragma unroll
    for (int t = 0; t < 4; t++) {
      af[t]  = *(const short8*)(Ap + (wm + t * 16 + (ln & 15)) * 32 + (ln >> 4) * 8);
      bfr[t] = *(const short8*)(Bp + (wn + t * 16 + (ln & 15)) * 32 + (ln >> 4) * 8);
    }
#pragma unroll
    for (int ti = 0; ti < 4; ti++)
#pragma unroll
      for (int tj = 0; tj < 4; tj++)
        acc[ti][tj] = MFMA16(af[ti], bfr[tj], acc[ti][tj]);
  }
  // epilogue: C/D layout col=lane&15, row=(lane>>4)*4+r  [m89-verified]
#pragma unroll
  for (int ti = 0; ti < 4; ti++)
#pragma unroll
    for (int tj = 0; tj < 4; tj++)
#pragma unroll
      for (int r = 0; r < 4; r++) {
        const int m = m0 + wm + ti * 16 + (ln >> 4) * 4 + r;
        const int n = n0 + wn + tj * 16 + (ln & 15);
        if (mode == 2) {
          OutF[(size_t)m * 1024 + n] = scrub(acc[ti][tj][r]);  // FP32 OUT
        } else {
          const int b = m >> 11, s = m & 2047;
          const int h = s >> 7, sl = s & 127;
          const int oc = n >> 6, d = n & 63;
          const int t = sl * 16 + oc;     // reshape-mixed "sequence" index
          size_t idx;
          if (mode == 0) idx = ((size_t)(b * 16 + h) * 2048 + t) * 64 + d;
          else           idx = ((size_t)(b * 16 + h) * 64 + d) * 2048 + t;
          Out[idx] = __float2bfloat16(scrub(acc[ti][tj][r]));
        }
      }
}

__global__ __launch_bounds__(256, 2) void k_proj(
    const void* __restrict__ q, const void* __restrict__ k, const void* __restrict__ v,
    const void* __restrict__ wq, const void* __restrict__ wk, const void* __restrict__ wvv,
    bf16* __restrict__ QH, bf16* __restrict__ KH, bf16* __restrict__ VT,
    const int* __restrict__ flags) {
  const int z = blockIdx.z;
  const int fl = flags[0];
  const void* A = (z == 0) ? q : (z == 1) ? k : v;
  const void* W = (z == 0) ? wq : (z == 1) ? wk : wvv;
  bf16* O = (z == 0) ? QH : (z == 1) ? KH : VT;
  gemm128(A, fl, W, fl, O, nullptr, (z == 2) ? 1 : 0);
}

__global__ __launch_bounds__(256, 2) void k_outp(
    const bf16* __restrict__ A, const void* __restrict__ W,
    float* __restrict__ Out, const int* __restrict__ flags) {
  gemm128(A, 0, W, flags[0], nullptr, Out, 2);
}

// ---------------------------------------------------------------------------
// Flash attention per (b,h). Wave w owns q-rows [32w,32w+32); row stats via
// shfl over 16-lane quads; P round-trips through LDS (C->A layout, m120).
// Mask: nonzero = EXCLUDE (faithful to reference where(mask, -inf, u)).
// __launch_bounds__(256,2): w/o it hipcc capped VGPR at 64 -> massive
// scratch spills (R8 profile: 730 MB/dispatch scratch traffic).
__global__ __launch_bounds__(256, 2) void k_attn(
    const bf16* __restrict__ QH, const bf16* __restrict__ KH,
    const bf16* __restrict__ VT, const void* __restrict__ maskp,
    const int* __restrict__ flags, bf16* __restrict__ OB) {
  constexpr int S = 2048, D = 64;
  constexpr float NEG = -30000.0f;
  __shared__ bf16 Qs[128 * 64];  // [t][d]
  __shared__ bf16 Ks[128 * 64];  // [t][d]
  __shared__ bf16 Vs[64 * 128];  // [d][t]
  __shared__ bf16 Ps[128 * 128]; // [q][k]
  const int tid = threadIdx.x, wv = tid >> 6, ln = tid & 63;
  const int q0 = blockIdx.x * 128;
  const int bh = blockIdx.y, b = bh >> 4, h = bh & 15;
  const int mmode = flags[1];
  const uint8_t*  mb = (const uint8_t*)maskp;
  const int*      mi = (const int*)maskp;
  const uint16_t* mh = (const uint16_t*)maskp;
  const uint32_t* mw = (const uint32_t*)maskp;
  const size_t mbase = (size_t)b * S * S;

  const bf16* Qg = QH + ((size_t)bh * S + q0) * D;
#pragma unroll
  for (int i = 0; i < 4; i++) {
    const int e = (i * 4 + wv) * 512 + ln * 8;
    *(short8*)(Qs + e) = *(const short8*)(Qg + e);
  }
  __syncthreads();
  short8 qf[2][2];
  {
    const short* Qp = (const short*)Qs;
#pragma unroll
    for (int ti = 0; ti < 2; ti++)
#pragma unroll
      for (int kc = 0; kc < 2; kc++)
        qf[ti][kc] = *(const short8*)(Qp + (wv * 32 + ti * 16 + (ln & 15)) * 64 + kc * 32 + (ln >> 4) * 8);
  }
  float mst[2][4], lst[2][4];
  floatx4 oacc[2][4] = {};
#pragma unroll
  for (int ti = 0; ti < 2; ti++)
#pragma unroll
    for (int r = 0; r < 4; r++) { mst[ti][r] = NEG; lst[ti][r] = 0.f; }

  for (int kt = 0; kt < 16; kt++) {
    __syncthreads();
    const bf16* Kg = KH + ((size_t)bh * S + kt * 128) * D;
#pragma unroll
    for (int i = 0; i < 4; i++) {
      const int e = (i * 4 + wv) * 512 + ln * 8;
      *(short8*)(Ks + e) = *(const short8*)(Kg + e);
    }
    const bf16* Vg = VT + (size_t)bh * D * S + kt * 128;
#pragma unroll
    for (int i = 0; i < 4; i++) {
      const int fb = ((i * 4 + wv) * 64 + ln) * 16;
      const int dd = fb >> 8, cb = (fb & 255) >> 1;
      *(short8*)(Vs + dd * 128 + cb) = *(const short8*)(Vg + (size_t)dd * S + cb);
    }
    __syncthreads();

    floatx4 sc[2][8];
    {
      const short* Kp = (const short*)Ks;
#pragma unroll
      for (int tj = 0; tj < 8; tj++) {
        const short8 k0f = *(const short8*)(Kp + (tj * 16 + (ln & 15)) * 64 + (ln >> 4) * 8);
        const short8 k1f = *(const short8*)(Kp + (tj * 16 + (ln & 15)) * 64 + 32 + (ln >> 4) * 8);
#pragma unroll
        for (int ti = 0; ti < 2; ti++) {
          floatx4 z = {0.f, 0.f, 0.f, 0.f};
          z = MFMA16(qf[ti][0], k0f, z);
          z = MFMA16(qf[ti][1], k1f, z);
          sc[ti][tj] = z;
        }
      }
    }
    float rmax[2][4];
#pragma unroll
    for (int ti = 0; ti < 2; ti++)
#pragma unroll
      for (int r = 0; r < 4; r++) rmax[ti][r] = NEG;
    const int kb = kt * 128;
#pragma unroll
    for (int ti = 0; ti < 2; ti++) {
      const int qr = q0 + wv * 32 + ti * 16 + (ln >> 4) * 4;
#pragma unroll
      for (int tj = 0; tj < 8; tj++) {
        const int kc = kb + tj * 16 + (ln & 15);
#pragma unroll
        for (int r = 0; r < 4; r++) {
          const size_t midx = mbase + (size_t)(qr + r) * S + kc;
          bool msk;  // nonzero = EXCLUDE (reference polarity)
          if (mmode == 1)      msk = (mi[midx] != 0);
          else if (mmode == 0) msk = (mb[midx] != 0);
          else if (mmode == 2) msk = (mh[midx] != 0);
          else                 msk = (mw[midx] != 0);
          float u = sc[ti][tj][r] * 0.125f;
          u = msk ? NEG : u;
          sc[ti][tj][r] = u;
          rmax[ti][r] = fmaxf(rmax[ti][r], u);
        }
      }
    }
    float alpha[2][4], mnew[2][4];
#pragma unroll
    for (int ti = 0; ti < 2; ti++)
#pragma unroll
      for (int r = 0; r < 4; r++) {
        float v = rmax[ti][r];
        v = fmaxf(v, __shfl_xor(v, 1));
        v = fmaxf(v, __shfl_xor(v, 2));
        v = fmaxf(v, __shfl_xor(v, 4));
        v = fmaxf(v, __shfl_xor(v, 8));
        const float mn = fmaxf(mst[ti][r], v);
        mnew[ti][r] = mn;
        alpha[ti][r] = __expf(fminf(mst[ti][r] - mn, 0.f));
        mst[ti][r] = mn;
      }
    float rsum[2][4] = {};
#pragma unroll
    for (int ti = 0; ti < 2; ti++) {
#pragma unroll
      for (int tj = 0; tj < 8; tj++) {
#pragma unroll
        for (int r = 0; r < 4; r++) {
          const float u = sc[ti][tj][r];
          const float p = (u <= NEG * 0.5f) ? 0.f : __expf(fminf(u - mnew[ti][r], 0.f));
          rsum[ti][r] += p;
          Ps[(wv * 32 + ti * 16 + (ln >> 4) * 4 + r) * 128 + tj * 16 + (ln & 15)] =
              __float2bfloat16(p);
        }
      }
    }
#pragma unroll
    for (int ti = 0; ti < 2; ti++)
#pragma unroll
      for (int r = 0; r < 4; r++) {
        float s = rsum[ti][r];
        s += __shfl_xor(s, 1);
        s += __shfl_xor(s, 2);
        s += __shfl_xor(s, 4);
        s += __shfl_xor(s, 8);
        lst[ti][r] = lst[ti][r] * alpha[ti][r] + s;
#pragma unroll
        for (int tj = 0; tj < 4; tj++) oacc[ti][tj][r] *= alpha[ti][r];
      }
    {
      const short* Pp = (const short*)Ps;
      const short* Vp = (const short*)Vs;
#pragma unroll
      for (int kc = 0; kc < 4; kc++) {
        short8 ap[2];
#pragma unroll
        for (int ti = 0; ti < 2; ti++)
          ap[ti] = *(const short8*)(Pp + (wv * 32 + ti * 16 + (ln & 15)) * 128 + kc * 32 + (ln >> 4) * 8);
#pragma unroll
        for (int tj = 0; tj < 4; tj++) {
          const short8 bv = *(const short8*)(Vp + (tj * 16 + (ln & 15)) * 128 + kc * 32 + (ln >> 4) * 8);
#pragma unroll
          for (int ti = 0; ti < 2; ti++) oacc[ti][tj] = MFMA16(ap[ti], bv, oacc[ti][tj]);
        }
      }
    }
  }
  // ---- epilogue: un-mix (h,t,d) -> (s,o), normalize ----
#pragma unroll
  for (int ti = 0; ti < 2; ti++)
#pragma unroll
    for (int r = 0; r < 4; r++) {
      const float li = lst[ti][r];
      const float rl = (li > 1e-30f) ? 1.f / li : 0.f;
      const int t = q0 + wv * 32 + ti * 16 + (ln >> 4) * 4 + r;
      const int s = h * 128 + (t >> 4);
#pragma unroll
      for (int tj = 0; tj < 4; tj++) {
        const int dcol = tj * 16 + (ln & 15);
        const int o = (t & 15) * 64 + dcol;
        OB[((size_t)b * S + s) * 1024 + o] = __float2bfloat16(scrub(oacc[ti][tj][r] * rl));
      }
    }
}

// ---------------------------------------------------------------------------
extern "C" void kernel_launch(void* const* d_in, const int* in_sizes, int n_in,
                              void* d_out, int out_size, void* d_ws, size_t ws_size,
                              hipStream_t stream) {
  const void* q  = d_in[0];
  const void* k  = d_in[1];
  const void* v  = d_in[2];
  const void* mask = d_in[3];
  const void* wq = d_in[4];
  const void* wk = d_in[5];
  const void* wv = d_in[6];
  const void* wo = d_in[7];
  float* out = (float*)d_out;   // FP32 output (reference output dtype)

  char* ws = (char*)d_ws;
  int* flags = (int*)ws;
  bf16* QH = (bf16*)(ws + 256);
  bf16* KH = QH + 4194304; // 2*16*2048*64
  bf16* VT = KH + 4194304;
  bf16* OB = VT + 4194304; // 32 MB + 256 B total

  k_detect<<<1, 256, 0, stream>>>((const uint16_t*)q, (const uint16_t*)mask, flags);
  k_proj<<<dim3(32, 8, 3), 256, 0, stream>>>(q, k, v, wq, wk, wv, QH, KH, VT, flags);
  k_attn<<<dim3(16, 32), 256, 0, stream>>>(QH, KH, VT, mask, flags, OB);
  k_outp<<<dim3(32, 8), 256, 0, stream>>>(OB, wo, out, flags);
}

// Round 10
// 475.437 us; speedup vs baseline: 1.8543x; 1.4794x over previous
//
#include <hip/hip_runtime.h>
#include <hip/hip_bf16.h>
#include <stdint.h>

// ============================================================================
// MultiHeadAttention, B=2 S=2048 D_MODEL=1024 NHEAD=16 D_HEAD=64.
// Inputs fp32 (runtime-sniffed, bf16 fallback); mask encoding classified;
// output fp32. Internal compute: bf16 MFMA, fp32 accumulate.
//
// SEMANTICS: faithful to the visible reference. (x @ W.T).reshape(B,16,-1,64)
// on (B,2048,1024) row-major MIXES seq and feature dims:
//   head h   = s >> 7
//   t (2048) = (s & 127)*16 + (o >> 6)
//   d (64)   = o & 63
// Attention runs over t; mask[b, t_q, t_k] aligns with t; True = EXCLUDE.
//
// R9:  k_attn spill-bound (VGPR=64) -> __launch_bounds__(256,2). 882->703us.
// R10: k_attn latency-bound on 64 branchy per-element mask loads per lane
//      per K-tile (each in its own basic block -> per-load waitcnt; ~66k
//      cyc/tile observed, MfmaUtil 3%). Fix: k_maskpack ballot-packs mask
//      to 1MB bitmask; k_attn reads 8 quad-broadcast dwordx4 bit words per
//      lane per tile. Also: OB aliases QH (un-mix permutation is the exact
//      inverse of the mix => identical flat layout; each block writes only
//      rows it alone reads, after reading them).
//
// Pipeline:
//   k_detect   : flags[0]=inputs-fp32, flags[1]=mask mode 0:u8 1:i32 2:u16 3:u32
//   k_maskpack : mask -> bitmask (bit=1 means EXCLUDE), 1 MB
//   k_proj     : z=0,1,2 -> QH/KH [b,h,t,d] and VT [b,h,d,t]  (128x128 GEMM)
//   k_attn     : flash attention per (b,h), 128x128 tiles, online softmax
//   k_outp     : OB(=QH) @ w_o.T -> d_out (FP32)
// Workspace: flags@0; QH(=OB)@256; KH@256+8M; VT@256+16M; bits@256+24M.
// ============================================================================

typedef __attribute__((ext_vector_type(8))) short short8;
typedef __attribute__((ext_vector_type(4))) float floatx4;
using bf16 = __hip_bfloat16;

#define MFMA16(a, b, c) __builtin_amdgcn_mfma_f32_16x16x32_bf16(a, b, c, 0, 0, 0)

__device__ __forceinline__ void load_lds16(const bf16* g, bf16* l) {
  __builtin_amdgcn_global_load_lds(
      (const __attribute__((address_space(1))) void*)g,
      (__attribute__((address_space(3))) void*)l, 16, 0, 0);
}

__device__ __forceinline__ float scrub(float x) {
  return (x == x && fabsf(x) < 1e30f) ? x : 0.0f;
}

// ---------------------------------------------------------------------------
__global__ void k_detect(const uint16_t* __restrict__ q,
                         const uint16_t* __restrict__ mask,
                         int* __restrict__ flags) {
  __shared__ int f32, cat;
  const int tid = threadIdx.x;
  if (tid == 0) { f32 = 0; cat = 0; }
  __syncthreads();
  int hit = 0;
  for (int i = tid; i < 16384; i += 256) {
    const int e = (q[i] >> 7) & 0xFF;
    if (e == 0 || e == 0xFF) hit = 1;   // impossible for bf16 N(0,1)
  }
  if (hit) atomicOr(&f32, 1);
  int c = 0;
  for (int i = tid; i < 2048; i += 256) {
    const uint32_t hw = mask[i];
    if (hw == 0x3C00u) c |= 4;                     // f16 1.0
    else if (hw == 0x3F80u) c |= (i & 1) ? 2 : 1;  // bf16(even)/fp32(odd half)
    else if (hw > 1u) c |= 8;                      // packed-byte pattern
  }
  if (c) atomicOr(&cat, c);
  __syncthreads();
  if (tid == 0) {
    flags[0] = f32;
    const int cc = cat;
    int mode;
    if (cc & 4)      mode = 2;
    else if (cc & 1) mode = 2;
    else if (cc & 2) mode = 3;
    else if (cc & 8) mode = 0;
    else             mode = 1;
    flags[1] = mode;
  }
}

// ---------------------------------------------------------------------------
// Pack mask (any of 4 encodings) into a bitmask: bit=1 <=> nonzero <=> EXCLUDE.
// Element e -> word e/32, bit e%32. Ballot over the wave: 64 elems -> 2 words.
__global__ __launch_bounds__(256) void k_maskpack(const void* __restrict__ maskp,
                                                  const int* __restrict__ flags,
                                                  uint32_t* __restrict__ bits) {
  const int mmode = flags[1];
  const int gtid = blockIdx.x * 256 + threadIdx.x;
  const int wid = gtid >> 6, ln = gtid & 63;
  const int nw = (gridDim.x * 256) >> 6;
  const int NG = 2 * 2048 * 2048 / 64;  // 131072 groups of 64
  for (int g = wid; g < NG; g += nw) {
    const size_t e = (size_t)g * 64 + ln;
    bool v;
    if (mmode == 1)      v = ((const int*)maskp)[e] != 0;
    else if (mmode == 0) v = ((const uint8_t*)maskp)[e] != 0;
    else if (mmode == 2) v = ((const uint16_t*)maskp)[e] != 0;
    else                 v = ((const uint32_t*)maskp)[e] != 0;
    const unsigned long long m = __ballot(v);
    if (ln == 0)       bits[(size_t)g * 2]     = (uint32_t)m;
    else if (ln == 32) bits[(size_t)g * 2 + 1] = (uint32_t)(m >> 32);
  }
}

// ---------------------------------------------------------------------------
// Tile staging: fill a 128x32 bf16 tile (8KB, row stride 32) from a source
// with row stride 1024 elements.
__device__ __forceinline__ void stage_b16(const bf16* __restrict__ src,
                                          bf16* __restrict__ dst,
                                          int wv, int ln) {
#pragma unroll
  for (int i = 0; i < 2; i++) {
    const int seg = i * 4 + wv;
    const int fb = seg * 1024 + ln * 16;
    const int row = fb >> 6, col = (fb & 63) >> 1;
    load_lds16(src + (size_t)row * 1024 + col, dst + seg * 512);
  }
}

__device__ __forceinline__ void stage_f32(const float* __restrict__ src,
                                          bf16* __restrict__ dst, int tid) {
#pragma unroll
  for (int it = 0; it < 2; ++it) {
    const int e0 = (it * 256 + tid) * 8;
    const int row = e0 >> 5, col = e0 & 31;
    const float* s = src + (size_t)row * 1024 + col;
    const float4 f0 = *(const float4*)s;
    const float4 f1 = *(const float4*)(s + 4);
    union { short8 v; bf16 b[8]; } u;
    u.b[0] = __float2bfloat16(f0.x); u.b[1] = __float2bfloat16(f0.y);
    u.b[2] = __float2bfloat16(f0.z); u.b[3] = __float2bfloat16(f0.w);
    u.b[4] = __float2bfloat16(f1.x); u.b[5] = __float2bfloat16(f1.y);
    u.b[6] = __float2bfloat16(f1.z); u.b[7] = __float2bfloat16(f1.w);
    *(short8*)(dst + e0) = u.v;
  }
}

// ---------------------------------------------------------------------------
// NT GEMM: A[M][1024], W[1024][1024] row-major, C[m][n]=sum_k A[m,k]W[n,k].
// 128x128 tile, BK=32, 4 waves (2x2 of 64x64).
// mode 0: C -> QH/KH [b,h,t,d] reshape-mixed;  mode 1: C -> VT [b,h,d,t];
// mode 2: C -> OutF (FP32, plain row-major).
__device__ __forceinline__ void gemm128(const void* __restrict__ A, int a_f32,
                                        const void* __restrict__ W, int w_f32,
                                        bf16* __restrict__ Out,
                                        float* __restrict__ OutF, int mode) {
  __shared__ bf16 As[128 * 32];
  __shared__ bf16 Bs[128 * 32];
  const int tid = threadIdx.x;
  const int wv = tid >> 6, ln = tid & 63;
  const int m0 = blockIdx.x * 128, n0 = blockIdx.y * 128;
  const int wm = (wv >> 1) * 64, wn = (wv & 1) * 64;
  floatx4 acc[4][4] = {};
  for (int k0 = 0; k0 < 1024; k0 += 32) {
    __syncthreads();
    if (a_f32) stage_f32((const float*)A + (size_t)m0 * 1024 + k0, As, tid);
    else       stage_b16((const bf16*)A + (size_t)m0 * 1024 + k0, As, wv, ln);
    if (w_f32) stage_f32((const float*)W + (size_t)n0 * 1024 + k0, Bs, tid);
    else       stage_b16((const bf16*)W + (size_t)n0 * 1024 + k0, Bs, wv, ln);
    __syncthreads();
    const short* Ap = (const short*)As;
    const short* Bp = (const short*)Bs;
    short8 af[4], bfr[4];
#pragma unroll
    for (int t = 0; t < 4; t++) {
      af[t]  = *(const short8*)(Ap + (wm + t * 16 + (ln & 15)) * 32 + (ln >> 4) * 8);
      bfr[t] = *(const short8*)(Bp + (wn + t * 16 + (ln & 15)) * 32 + (ln >> 4) * 8);
    }
#pragma unroll
    for (int ti = 0; ti < 4; ti++)
#pragma unroll
      for (int tj = 0; tj < 4; tj++)
        acc[ti][tj] = MFMA16(af[ti], bfr[tj], acc[ti][tj]);
  }
  // epilogue: C/D layout col=lane&15, row=(lane>>4)*4+r  [m89-verified]
#pragma unroll
  for (int ti = 0; ti < 4; ti++)
#pragma unroll
    for (int tj = 0; tj < 4; tj++)
#pragma unroll
      for (int r = 0; r < 4; r++) {
        const int m = m0 + wm + ti * 16 + (ln >> 4) * 4 + r;
        const int n = n0 + wn + tj * 16 + (ln & 15);
        if (mode == 2) {
          OutF[(size_t)m * 1024 + n] = scrub(acc[ti][tj][r]);  // FP32 OUT
        } else {
          const int b = m >> 11, s = m & 2047;
          const int h = s >> 7, sl = s & 127;
          const int oc = n >> 6, d = n & 63;
          const int t = sl * 16 + oc;     // reshape-mixed "sequence" index
          size_t idx;
          if (mode == 0) idx = ((size_t)(b * 16 + h) * 2048 + t) * 64 + d;
          else           idx = ((size_t)(b * 16 + h) * 64 + d) * 2048 + t;
          Out[idx] = __float2bfloat16(scrub(acc[ti][tj][r]));
        }
      }
}

__global__ __launch_bounds__(256, 2) void k_proj(
    const void* __restrict__ q, const void* __restrict__ k, const void* __restrict__ v,
    const void* __restrict__ wq, const void* __restrict__ wk, const void* __restrict__ wvv,
    bf16* __restrict__ QH, bf16* __restrict__ KH, bf16* __restrict__ VT,
    const int* __restrict__ flags) {
  const int z = blockIdx.z;
  const int fl = flags[0];
  const void* A = (z == 0) ? q : (z == 1) ? k : v;
  const void* W = (z == 0) ? wq : (z == 1) ? wk : wvv;
  bf16* O = (z == 0) ? QH : (z == 1) ? KH : VT;
  gemm128(A, fl, W, fl, O, nullptr, (z == 2) ? 1 : 0);
}

__global__ __launch_bounds__(256, 2) void k_outp(
    const bf16* __restrict__ A, const void* __restrict__ W,
    float* __restrict__ Out, const int* __restrict__ flags) {
  gemm128(A, 0, W, flags[0], nullptr, Out, 2);
}

// ---------------------------------------------------------------------------
// Flash attention per (b,h). Wave w owns q-rows [32w,32w+32); row stats via
// shfl over 16-lane quads; P round-trips through LDS (C->A layout, m120).
// Mask from 1MB bitmask: per (ti,r) one dwordx4 (quad-broadcast, L2-hot),
// bit=1 => EXCLUDE. OB aliases QH (see header note).
__global__ __launch_bounds__(256, 2) void k_attn(
    const bf16* __restrict__ QH, const bf16* __restrict__ KH,
    const bf16* __restrict__ VT, const uint32_t* __restrict__ bits,
    bf16* __restrict__ OB) {
  constexpr int S = 2048, D = 64;
  constexpr float NEG = -30000.0f;
  __shared__ bf16 Qs[128 * 64];  // [t][d]
  __shared__ bf16 Ks[128 * 64];  // [t][d]
  __shared__ bf16 Vs[64 * 128];  // [d][t]
  __shared__ bf16 Ps[128 * 128]; // [q][k]
  const int tid = threadIdx.x, wv = tid >> 6, ln = tid & 63;
  const int q0 = blockIdx.x * 128;
  const int bh = blockIdx.y, b = bh >> 4, h = bh & 15;

  const bf16* Qg = QH + ((size_t)bh * S + q0) * D;
#pragma unroll
  for (int i = 0; i < 4; i++) {
    const int e = (i * 4 + wv) * 512 + ln * 8;
    *(short8*)(Qs + e) = *(const short8*)(Qg + e);
  }
  __syncthreads();
  short8 qf[2][2];
  {
    const short* Qp = (const short*)Qs;
#pragma unroll
    for (int ti = 0; ti < 2; ti++)
#pragma unroll
      for (int kc = 0; kc < 2; kc++)
        qf[ti][kc] = *(const short8*)(Qp + (wv * 32 + ti * 16 + (ln & 15)) * 64 + kc * 32 + (ln >> 4) * 8);
  }
  float mst[2][4], lst[2][4];
  floatx4 oacc[2][4] = {};
#pragma unroll
  for (int ti = 0; ti < 2; ti++)
#pragma unroll
    for (int r = 0; r < 4; r++) { mst[ti][r] = NEG; lst[ti][r] = 0.f; }

  for (int kt = 0; kt < 16; kt++) {
    __syncthreads();
    const bf16* Kg = KH + ((size_t)bh * S + kt * 128) * D;
#pragma unroll
    for (int i = 0; i < 4; i++) {
      const int e = (i * 4 + wv) * 512 + ln * 8;
      *(short8*)(Ks + e) = *(const short8*)(Kg + e);
    }
    const bf16* Vg = VT + (size_t)bh * D * S + kt * 128;
#pragma unroll
    for (int i = 0; i < 4; i++) {
      const int fb = ((i * 4 + wv) * 64 + ln) * 16;
      const int dd = fb >> 8, cb = (fb & 255) >> 1;
      *(short8*)(Vs + dd * 128 + cb) = *(const short8*)(Vg + (size_t)dd * S + cb);
    }
    __syncthreads();

    floatx4 sc[2][8];
    {
      const short* Kp = (const short*)Ks;
#pragma unroll
      for (int tj = 0; tj < 8; tj++) {
        const short8 k0f = *(const short8*)(Kp + (tj * 16 + (ln & 15)) * 64 + (ln >> 4) * 8);
        const short8 k1f = *(const short8*)(Kp + (tj * 16 + (ln & 15)) * 64 + 32 + (ln >> 4) * 8);
#pragma unroll
        for (int ti = 0; ti < 2; ti++) {
          floatx4 z = {0.f, 0.f, 0.f, 0.f};
          z = MFMA16(qf[ti][0], k0f, z);
          z = MFMA16(qf[ti][1], k1f, z);
          sc[ti][tj] = z;
        }
      }
    }
    // ---- scale + mask (bitmask, unconditional loads) + rowmax ----
    float rmax[2][4];
#pragma unroll
    for (int ti = 0; ti < 2; ti++)
#pragma unroll
      for (int r = 0; r < 4; r++) rmax[ti][r] = NEG;
    const uint32_t* Mb = bits + (size_t)b * 131072 + kt * 4;
#pragma unroll
    for (int ti = 0; ti < 2; ti++) {
      const int qr = q0 + wv * 32 + ti * 16 + (ln >> 4) * 4;
#pragma unroll
      for (int r = 0; r < 4; r++) {
        const uint4 mv = *(const uint4*)(Mb + (size_t)(qr + r) * 64);
        const uint32_t mw4[4] = {mv.x, mv.y, mv.z, mv.w};
#pragma unroll
        for (int tj = 0; tj < 8; tj++) {
          const bool msk =
              ((mw4[tj >> 1] >> (((tj & 1) << 4) + (ln & 15))) & 1u) != 0u;
          float u = sc[ti][tj][r] * 0.125f;
          u = msk ? NEG : u;
          sc[ti][tj][r] = u;
          rmax[ti][r] = fmaxf(rmax[ti][r], u);
        }
      }
    }
    float alpha[2][4], mnew[2][4];
#pragma unroll
    for (int ti = 0; ti < 2; ti++)
#pragma unroll
      for (int r = 0; r < 4; r++) {
        float v = rmax[ti][r];
        v = fmaxf(v, __shfl_xor(v, 1));
        v = fmaxf(v, __shfl_xor(v, 2));
        v = fmaxf(v, __shfl_xor(v, 4));
        v = fmaxf(v, __shfl_xor(v, 8));
        const float mn = fmaxf(mst[ti][r], v);
        mnew[ti][r] = mn;
        alpha[ti][r] = __expf(fminf(mst[ti][r] - mn, 0.f));
        mst[ti][r] = mn;
      }
    float rsum[2][4] = {};
#pragma unroll
    for (int ti = 0; ti < 2; ti++) {
#pragma unroll
      for (int tj = 0; tj < 8; tj++) {
#pragma unroll
        for (int r = 0; r < 4; r++) {
          const float u = sc[ti][tj][r];
          const float p = (u <= NEG * 0.5f) ? 0.f : __expf(fminf(u - mnew[ti][r], 0.f));
          rsum[ti][r] += p;
          Ps[(wv * 32 + ti * 16 + (ln >> 4) * 4 + r) * 128 + tj * 16 + (ln & 15)] =
              __float2bfloat16(p);
        }
      }
    }
#pragma unroll
    for (int ti = 0; ti < 2; ti++)
#pragma unroll
      for (int r = 0; r < 4; r++) {
        float s = rsum[ti][r];
        s += __shfl_xor(s, 1);
        s += __shfl_xor(s, 2);
        s += __shfl_xor(s, 4);
        s += __shfl_xor(s, 8);
        lst[ti][r] = lst[ti][r] * alpha[ti][r] + s;
#pragma unroll
        for (int tj = 0; tj < 4; tj++) oacc[ti][tj][r] *= alpha[ti][r];
      }
    {
      const short* Pp = (const short*)Ps;
      const short* Vp = (const short*)Vs;
#pragma unroll
      for (int kc = 0; kc < 4; kc++) {
        short8 ap[2];
#pragma unroll
        for (int ti = 0; ti < 2; ti++)
          ap[ti] = *(const short8*)(Pp + (wv * 32 + ti * 16 + (ln & 15)) * 128 + kc * 32 + (ln >> 4) * 8);
#pragma unroll
        for (int tj = 0; tj < 4; tj++) {
          const short8 bv = *(const short8*)(Vp + (tj * 16 + (ln & 15)) * 128 + kc * 32 + (ln >> 4) * 8);
#pragma unroll
          for (int ti = 0; ti < 2; ti++) oacc[ti][tj] = MFMA16(ap[ti], bv, oacc[ti][tj]);
        }
      }
    }
  }
  // ---- epilogue: un-mix (h,t,d) -> (s,o), normalize ----
#pragma unroll
  for (int ti = 0; ti < 2; ti++)
#pragma unroll
    for (int r = 0; r < 4; r++) {
      const float li = lst[ti][r];
      const float rl = (li > 1e-30f) ? 1.f / li : 0.f;
      const int t = q0 + wv * 32 + ti * 16 + (ln >> 4) * 4 + r;
      const int s = h * 128 + (t >> 4);
#pragma unroll
      for (int tj = 0; tj < 4; tj++) {
        const int dcol = tj * 16 + (ln & 15);
        const int o = (t & 15) * 64 + dcol;
        OB[((size_t)b * S + s) * 1024 + o] = __float2bfloat16(scrub(oacc[ti][tj][r] * rl));
      }
    }
}

// ---------------------------------------------------------------------------
extern "C" void kernel_launch(void* const* d_in, const int* in_sizes, int n_in,
                              void* d_out, int out_size, void* d_ws, size_t ws_size,
                              hipStream_t stream) {
  const void* q  = d_in[0];
  const void* k  = d_in[1];
  const void* v  = d_in[2];
  const void* mask = d_in[3];
  const void* wq = d_in[4];
  const void* wk = d_in[5];
  const void* wv = d_in[6];
  const void* wo = d_in[7];
  float* out = (float*)d_out;   // FP32 output (reference output dtype)

  char* ws = (char*)d_ws;
  int* flags = (int*)ws;
  bf16* QH = (bf16*)(ws + 256);     // also OB (aliasing proven safe)
  bf16* KH = QH + 4194304;          // 2*16*2048*64
  bf16* VT = KH + 4194304;
  uint32_t* bits = (uint32_t*)(VT + 4194304);  // 1 MB; total 25 MB + 256 B

  k_detect<<<1, 256, 0, stream>>>((const uint16_t*)q, (const uint16_t*)mask, flags);
  k_maskpack<<<256, 256, 0, stream>>>(mask, flags, bits);
  k_proj<<<dim3(32, 8, 3), 256, 0, stream>>>(q, k, v, wq, wk, wv, QH, KH, VT, flags);
  k_attn<<<dim3(16, 32), 256, 0, stream>>>(QH, KH, VT, bits, QH /*OB alias*/);
  k_outp<<<dim3(32, 8), 256, 0, stream>>>(QH, wo, out, flags);
}